// Round 9
// baseline (127.228 us; speedup 1.0000x reference)
//
#include <hip/hip_runtime.h>
#include <hip/hip_bf16.h>
#include <math.h>

typedef __attribute__((ext_vector_type(4))) float f32x4;
typedef __attribute__((ext_vector_type(8))) short bf16x8;     // 8 bf16 in 4 VGPRs
typedef __attribute__((ext_vector_type(4))) unsigned short u16x4;
typedef __attribute__((ext_vector_type(8))) unsigned short u16x8;
typedef __attribute__((ext_vector_type(2))) unsigned int u32x2;

__device__ __forceinline__ unsigned short f2b(float f) {
  unsigned int u = __builtin_bit_cast(unsigned int, f);
  u += 0x7fffu + ((u >> 16) & 1u);          // RNE
  return (unsigned short)(u >> 16);
}
__device__ __forceinline__ float gelu_exact(float x) {
  return 0.5f * x * (1.0f + erff(x * 0.70710678118654752440f));
}

// ---------------- prep: token MLP hiddens + weight conversions (one small kernel) ----
__global__ void prep(const float* __restrict__ tokens,
                     const float* __restrict__ Wk1, const float* __restrict__ Wv1,
                     const float* __restrict__ Wk2, const float* __restrict__ Wv2,
                     unsigned short* __restrict__ hkb, unsigned short* __restrict__ hvTb,
                     unsigned short* __restrict__ Wk2b, unsigned short* __restrict__ Wv2Tb) {
  const int tid = threadIdx.x;
  const int bx = blockIdx.x;
  if (bx < 256) {
    __shared__ float tok[4][64];
    const int tl = tid >> 6, j = tid & 63;
    const int t0 = bx * 4;
    tok[tl][j] = tokens[(size_t)(t0 + tl) * 64 + j];
    __syncthreads();
    float sk = 0.f, sv = 0.f;
    #pragma unroll 16
    for (int i = 0; i < 64; ++i) {
      float tv = tok[tl][i];
      sk += tv * Wk1[i * 64 + j];
      sv += tv * Wv1[i * 64 + j];
    }
    hkb[(size_t)(t0 + tl) * 64 + j]  = f2b(gelu_exact(sk));
    hvTb[(size_t)j * 1024 + t0 + tl] = f2b(gelu_exact(sv));
  } else if (bx < 272) {
    const int b = bx - 256;
    for (int i = 0; i < 8; ++i) {
      int idx = b * 2048 + i * 256 + tid;
      f32x4 v = ((const f32x4*)Wk2)[idx];
      u16x4 o; o[0] = f2b(v[0]); o[1] = f2b(v[1]); o[2] = f2b(v[2]); o[3] = f2b(v[3]);
      ((u16x4*)Wk2b)[idx] = o;
    }
  } else {
    __shared__ float t[64][65];
    const int f0 = (bx - 272) * 64;
    for (int i = 0; i < 16; ++i) {
      int idx = i * 256 + tid; int r = idx >> 6, c = idx & 63;   // r=j, c=f
      t[r][c] = Wv2[(size_t)r * 2048 + f0 + c];
    }
    __syncthreads();
    for (int i = 0; i < 16; ++i) {
      int idx = i * 256 + tid; int r = idx >> 6, c = idx & 63;   // r=f, c=j
      Wv2Tb[(size_t)(f0 + r) * 64 + c] = f2b(t[c][r]);
    }
  }
}

// ---------------- main: x[16 rows] -> xp -> sim -> norm/gelu -> wv -> out, one pass ----
// 1024 blocks x 256 thr, 16 x-rows per block. All intermediates in regs/LDS.
__global__ __launch_bounds__(256, 4)
void mainK(const float* __restrict__ x,
           const unsigned short* __restrict__ Wk2b,
           const unsigned short* __restrict__ hkb,
           const unsigned short* __restrict__ hvTb,
           const unsigned short* __restrict__ Wv2Tb,
           float* __restrict__ out) {
  __shared__ float redbuf[4][4][64][4];          // 16 KB: xp partials, later wv partials
  __shared__ unsigned short Pl[4][16][152];      // 19 KB: wave-private P chunks
  __shared__ unsigned short xw16[16][72];        // 2.3 KB: xp16, later wv16
  __shared__ float redn[4][16];                  // norm partials

  const int tid = threadIdx.x;
  const int wave = tid >> 6, lane = tid & 63;
  const int lrow = lane & 15, q = lane >> 4;
  const int r0 = blockIdx.x * 16;
  const int tw = wave * 256;                     // wave's token stripe

  // ---- phase 1: xp = x16 @ Wk2b^T (wave K-split 4x512, LDS reduce) ----
  {
    f32x4 accp[4] = {};
    const int kbase = wave * 512;
    #pragma unroll 4
    for (int s = 0; s < 8; ++s) {
      const int k0 = kbase + s * 64;
      bf16x8 a[2];
      #pragma unroll
      for (int kk = 0; kk < 2; ++kk) {
        const float* p = &x[(size_t)(r0 + lrow) * 2048 + k0 + kk * 32 + q * 8];
        f32x4 lo = *(const f32x4*)p;
        f32x4 hi = *(const f32x4*)(p + 4);
        u16x8 t;
        t[0] = f2b(lo[0]); t[1] = f2b(lo[1]); t[2] = f2b(lo[2]); t[3] = f2b(lo[3]);
        t[4] = f2b(hi[0]); t[5] = f2b(hi[1]); t[6] = f2b(hi[2]); t[7] = f2b(hi[3]);
        a[kk] = __builtin_bit_cast(bf16x8, t);
      }
      #pragma unroll
      for (int nt = 0; nt < 4; ++nt)
        #pragma unroll
        for (int kk = 0; kk < 2; ++kk) {
          bf16x8 b = *(const bf16x8*)&Wk2b[(size_t)(nt * 16 + lrow) * 2048 + k0 + kk * 32 + q * 8];
          accp[nt] = __builtin_amdgcn_mfma_f32_16x16x32_bf16(a[kk], b, accp[nt], 0, 0, 0);
        }
    }
    #pragma unroll
    for (int nt = 0; nt < 4; ++nt)
      *(f32x4*)&redbuf[wave][nt][lane][0] = accp[nt];
  }
  __syncthreads();
  {
    f32x4 s = *(const f32x4*)&redbuf[0][wave][lane][0];
    s += *(const f32x4*)&redbuf[1][wave][lane][0];
    s += *(const f32x4*)&redbuf[2][wave][lane][0];
    s += *(const f32x4*)&redbuf[3][wave][lane][0];
    #pragma unroll
    for (int r = 0; r < 4; ++r)
      xw16[q * 4 + r][wave * 16 + lrow] = f2b(s[r]);   // xp16[row][col]
  }
  __syncthreads();

  // ---- phase 2: simT for this wave's 256-token stripe (swapped mfma) ----
  bf16x8 xb[2];
  #pragma unroll
  for (int kk = 0; kk < 2; ++kk)
    xb[kk] = *(const bf16x8*)&xw16[lrow][kk * 32 + q * 8];   // B-frag: xp row = lrow
  f32x4 acc[16] = {};
  #pragma unroll
  for (int t16 = 0; t16 < 16; ++t16)
    #pragma unroll
    for (int kk = 0; kk < 2; ++kk) {
      bf16x8 a = *(const bf16x8*)&hkb[(size_t)(tw + t16 * 16 + lrow) * 64 + kk * 32 + q * 8];
      acc[t16] = __builtin_amdgcn_mfma_f32_16x16x32_bf16(a, xb[kk], acc[t16], 0, 0, 0);
    }

  // ---- phase 3: row sumsq -> scale (sim row = lrow) ----
  float ss = 0.f;
  #pragma unroll
  for (int t16 = 0; t16 < 16; ++t16)
    #pragma unroll
    for (int r = 0; r < 4; ++r)
      ss += acc[t16][r] * acc[t16][r];
  ss += __shfl_xor(ss, 16, 64);
  ss += __shfl_xor(ss, 32, 64);
  if (q == 0) redn[wave][lrow] = ss;
  __syncthreads();
  const float scale = 32.0f * rsqrtf(fmaxf(
      redn[0][lrow] + redn[1][lrow] + redn[2][lrow] + redn[3][lrow], 1e-20f));

  // ---- phase 4: P chunks (gelu) + wv partial ----
  f32x4 wva[4] = {};
  #pragma unroll
  for (int c = 0; c < 2; ++c) {
    #pragma unroll
    for (int t8 = 0; t8 < 8; ++t8) {
      const int t16 = c * 8 + t8;
      float g0 = gelu_exact(acc[t16][0] * scale);
      float g1 = gelu_exact(acc[t16][1] * scale);
      float g2 = gelu_exact(acc[t16][2] * scale);
      float g3 = gelu_exact(acc[t16][3] * scale);
      u32x2 pw;
      pw[0] = (unsigned)f2b(g0) | ((unsigned)f2b(g1) << 16);
      pw[1] = (unsigned)f2b(g2) | ((unsigned)f2b(g3) << 16);
      *(u32x2*)&Pl[wave][lrow][t8 * 16 + q * 4] = pw;        // chunk-local token t8*16+q*4
    }
    #pragma unroll
    for (int kc = 0; kc < 4; ++kc) {
      bf16x8 pa = *(const bf16x8*)&Pl[wave][lrow][kc * 32 + q * 8];
      #pragma unroll
      for (int nt = 0; nt < 4; ++nt) {
        bf16x8 b = *(const bf16x8*)&hvTb[(size_t)(nt * 16 + lrow) * 1024 +
                                         tw + c * 128 + kc * 32 + q * 8];
        wva[nt] = __builtin_amdgcn_mfma_f32_16x16x32_bf16(pa, b, wva[nt], 0, 0, 0);
      }
    }
  }

  // ---- phase 5: wv cross-wave reduce -> wv16 (reuse redbuf, xw16) ----
  #pragma unroll
  for (int nt = 0; nt < 4; ++nt)
    *(f32x4*)&redbuf[wave][nt][lane][0] = wva[nt];
  __syncthreads();
  {
    f32x4 s = *(const f32x4*)&redbuf[0][wave][lane][0];
    s += *(const f32x4*)&redbuf[1][wave][lane][0];
    s += *(const f32x4*)&redbuf[2][wave][lane][0];
    s += *(const f32x4*)&redbuf[3][wave][lane][0];
    #pragma unroll
    for (int r = 0; r < 4; ++r)
      xw16[q * 4 + r][wave * 16 + lrow] = f2b(s[r]);   // wv16[row][j]
  }
  __syncthreads();

  // ---- phase 6: out = wv16 @ Wv2T^T, SWAPPED mfma -> lane holds 4 consecutive
  //      out-cols of ONE row -> fully-coalesced f32x4 stores (16 rows x 64 B / instr).
  //      D = A(Wv2T rows) . B(wv16 rows)^T ; lane(lrow,q): out[r0+lrow][tile + q*4+r].
  bf16x8 bw[2];
  #pragma unroll
  for (int kk = 0; kk < 2; ++kk)
    bw[kk] = *(const bf16x8*)&xw16[lrow][kk * 32 + q * 8];
  const int c0 = wave * 512;
  #pragma unroll 1
  for (int nf = 0; nf < 4; ++nf) {
    f32x4 acc2[8] = {};
    #pragma unroll
    for (int nt = 0; nt < 8; ++nt) {
      const int frow = c0 + nf * 128 + nt * 16 + lrow;
      bf16x8 a0 = *(const bf16x8*)&Wv2Tb[(size_t)frow * 64 + q * 8];
      bf16x8 a1 = *(const bf16x8*)&Wv2Tb[(size_t)frow * 64 + 32 + q * 8];
      acc2[nt] = __builtin_amdgcn_mfma_f32_16x16x32_bf16(a0, bw[0], acc2[nt], 0, 0, 0);
      acc2[nt] = __builtin_amdgcn_mfma_f32_16x16x32_bf16(a1, bw[1], acc2[nt], 0, 0, 0);
    }
    #pragma unroll
    for (int nt = 0; nt < 8; ++nt)
      *(f32x4*)&out[(size_t)(r0 + lrow) * 2048 + c0 + nf * 128 + nt * 16 + q * 4] = acc2[nt];
  }
}

extern "C" void kernel_launch(void* const* d_in, const int* in_sizes, int n_in,
                              void* d_out, int out_size, void* d_ws, size_t ws_size,
                              hipStream_t stream) {
  (void)in_sizes; (void)n_in; (void)out_size; (void)ws_size;
  const float* x      = (const float*)d_in[0];
  const float* tokens = (const float*)d_in[1];
  const float* Wk1    = (const float*)d_in[2];
  const float* Wk2    = (const float*)d_in[3];
  const float* Wv1    = (const float*)d_in[4];
  const float* Wv2    = (const float*)d_in[5];

  char* ws = (char*)d_ws;
  unsigned short* hkb   = (unsigned short*)(ws);                    // 128 KB
  unsigned short* hvTb  = (unsigned short*)(ws + 131072);           // 128 KB
  unsigned short* Wk2b  = (unsigned short*)(ws + 262144);           // 256 KB
  unsigned short* Wv2Tb = (unsigned short*)(ws + 524288);           // 256 KB

  hipLaunchKernelGGL(prep, dim3(304), dim3(256), 0, stream,
                     tokens, Wk1, Wv1, Wk2, Wv2, hkb, hvTb, Wk2b, Wv2Tb);
  hipLaunchKernelGGL(mainK, dim3(1024), dim3(256), 0, stream,
                     x, Wk2b, hkb, hvTb, Wv2Tb, (float*)d_out);
}

// Round 10
// 109.945 us; speedup vs baseline: 1.1572x; 1.1572x over previous
//
#include <hip/hip_runtime.h>
#include <hip/hip_bf16.h>
#include <math.h>

typedef __attribute__((ext_vector_type(4))) float f32x4;
typedef __attribute__((ext_vector_type(8))) short bf16x8;     // 8 bf16 in 4 VGPRs
typedef __attribute__((ext_vector_type(4))) unsigned short u16x4;
typedef __attribute__((ext_vector_type(8))) unsigned short u16x8;
typedef __attribute__((ext_vector_type(2))) unsigned int u32x2;

__device__ __forceinline__ unsigned short f2b(float f) {
  unsigned int u = __builtin_bit_cast(unsigned int, f);
  u += 0x7fffu + ((u >> 16) & 1u);          // RNE
  return (unsigned short)(u >> 16);
}
__device__ __forceinline__ float gelu_exact(float x) {
  return 0.5f * x * (1.0f + erff(x * 0.70710678118654752440f));
}

// ---------------- prep: token MLP hiddens + weight conversions ----------------
__global__ void prep(const float* __restrict__ tokens,
                     const float* __restrict__ Wk1, const float* __restrict__ Wv1,
                     const float* __restrict__ Wk2, const float* __restrict__ Wv2,
                     unsigned short* __restrict__ hkb, unsigned short* __restrict__ hvTb,
                     unsigned short* __restrict__ Wk2b, unsigned short* __restrict__ Wv2Tb) {
  const int tid = threadIdx.x;
  const int bx = blockIdx.x;
  if (bx < 256) {
    __shared__ float tok[4][64];
    const int tl = tid >> 6, j = tid & 63;
    const int t0 = bx * 4;
    tok[tl][j] = tokens[(size_t)(t0 + tl) * 64 + j];
    __syncthreads();
    float sk = 0.f, sv = 0.f;
    #pragma unroll 16
    for (int i = 0; i < 64; ++i) {
      float tv = tok[tl][i];
      sk += tv * Wk1[i * 64 + j];
      sv += tv * Wv1[i * 64 + j];
    }
    hkb[(size_t)(t0 + tl) * 64 + j]  = f2b(gelu_exact(sk));
    hvTb[(size_t)j * 1024 + t0 + tl] = f2b(gelu_exact(sv));
  } else if (bx < 272) {
    const int b = bx - 256;
    for (int i = 0; i < 8; ++i) {
      int idx = b * 2048 + i * 256 + tid;
      f32x4 v = ((const f32x4*)Wk2)[idx];
      u16x4 o; o[0] = f2b(v[0]); o[1] = f2b(v[1]); o[2] = f2b(v[2]); o[3] = f2b(v[3]);
      ((u16x4*)Wk2b)[idx] = o;
    }
  } else {
    __shared__ float t[64][65];
    const int f0 = (bx - 272) * 64;
    for (int i = 0; i < 16; ++i) {
      int idx = i * 256 + tid; int r = idx >> 6, c = idx & 63;   // r=j, c=f
      t[r][c] = Wv2[(size_t)r * 2048 + f0 + c];
    }
    __syncthreads();
    for (int i = 0; i < 16; ++i) {
      int idx = i * 256 + tid; int r = idx >> 6, c = idx & 63;   // r=f, c=j
      Wv2Tb[(size_t)(f0 + r) * 64 + c] = f2b(t[c][r]);
    }
  }
}

// ---------------- K1: xp[16384,64] = x @ Wk2b^T (LDS-staged, coalesced) ----------------
// 512 blocks x 32 rows x 4 waves (mt = w&1 m-tile, h = w>>1 K-half). BK=64 per half,
// 16 dbuf steps. x loads: 4 x 256B runs/instr; Wk2b: 8 x 128B runs/instr.
// LDS tiles XOR-swizzled in 16B units: col_u ^= row&7 (uniform-bank b128 reads).
__global__ __launch_bounds__(256)
void k1_xp(const float* __restrict__ x, const unsigned short* __restrict__ Wk2b,
           unsigned short* __restrict__ xp) {
  __shared__ unsigned short As[2][4096];   // [buf][(r*2+h)*64 + col]  32r x 2h x 64c
  __shared__ unsigned short Bs[2][8192];   // [buf][(t*2+h)*64 + col]  64t x 2h x 64c
  __shared__ float red[2][4][64][4];
  const int tid = threadIdx.x, wave = tid >> 6, lane = tid & 63;
  const int lrow = lane & 15, q = lane >> 4;
  const int mt = wave & 1, h = wave >> 1;
  const int r0 = blockIdx.x * 32;

  f32x4 aR[4]; u16x8 bR[4];
  f32x4 acc[4] = {};

  // ---- prologue: stage step 0 ----
  #pragma unroll
  for (int i = 0; i < 4; ++i) {
    int u4 = (wave * 4 + i) * 4 + (lane >> 4);
    int r = u4 >> 1, ah = u4 & 1;
    aR[i] = *(const f32x4*)&x[(size_t)(r0 + r) * 2048 + ah * 1024 + (lane & 15) * 4];
    int lin = (wave * 4 + i) * 8 + (lane >> 3);
    int t = lin >> 1, bh = lin & 1;
    bR[i] = *(const u16x8*)&Wk2b[(size_t)t * 2048 + bh * 1024 + (lane & 7) * 8];
  }
  #pragma unroll
  for (int i = 0; i < 4; ++i) {
    int u4 = (wave * 4 + i) * 4 + (lane >> 4);
    int r = u4 >> 1, ah = u4 & 1;
    int uu = ((lane & 15) >> 1) ^ (r & 7);
    u16x4 o;
    o[0] = f2b(aR[i][0]); o[1] = f2b(aR[i][1]); o[2] = f2b(aR[i][2]); o[3] = f2b(aR[i][3]);
    *(u16x4*)&As[0][(r * 2 + ah) * 64 + (uu << 3) + (lane & 1) * 4] = o;
    int lin = (wave * 4 + i) * 8 + (lane >> 3);
    int t = lin >> 1, bh = lin & 1;
    *(u16x8*)&Bs[0][(t * 2 + bh) * 64 + (((lane & 7) ^ (t & 7)) << 3)] = bR[i];
  }
  __syncthreads();

  #pragma unroll 1
  for (int s = 0; s < 16; ++s) {
    const int cb = s & 1, nb = cb ^ 1;
    const bool pf = (s + 1) < 16;
    // issue next-step loads (hide under compute)
    if (pf) {
      #pragma unroll
      for (int i = 0; i < 4; ++i) {
        int u4 = (wave * 4 + i) * 4 + (lane >> 4);
        int r = u4 >> 1, ah = u4 & 1;
        aR[i] = *(const f32x4*)&x[(size_t)(r0 + r) * 2048 + ah * 1024 + (s + 1) * 64 + (lane & 15) * 4];
        int lin = (wave * 4 + i) * 8 + (lane >> 3);
        int t = lin >> 1, bh = lin & 1;
        bR[i] = *(const u16x8*)&Wk2b[(size_t)t * 2048 + bh * 1024 + (s + 1) * 64 + (lane & 7) * 8];
      }
    }
    // compute current buffer
    #pragma unroll
    for (int kk = 0; kk < 2; ++kk) {
      const int ar = mt * 16 + lrow;
      bf16x8 af = *(const bf16x8*)&As[cb][(ar * 2 + h) * 64 + (((kk * 4 + q) ^ (ar & 7)) << 3)];
      #pragma unroll
      for (int nt = 0; nt < 4; ++nt) {
        const int br = nt * 16 + lrow;
        bf16x8 bf = *(const bf16x8*)&Bs[cb][(br * 2 + h) * 64 + (((kk * 4 + q) ^ (br & 7)) << 3)];
        acc[nt] = __builtin_amdgcn_mfma_f32_16x16x32_bf16(af, bf, acc[nt], 0, 0, 0);
      }
    }
    // write next buffer
    if (pf) {
      #pragma unroll
      for (int i = 0; i < 4; ++i) {
        int u4 = (wave * 4 + i) * 4 + (lane >> 4);
        int r = u4 >> 1, ah = u4 & 1;
        int uu = ((lane & 15) >> 1) ^ (r & 7);
        u16x4 o;
        o[0] = f2b(aR[i][0]); o[1] = f2b(aR[i][1]); o[2] = f2b(aR[i][2]); o[3] = f2b(aR[i][3]);
        *(u16x4*)&As[nb][(r * 2 + ah) * 64 + (uu << 3) + (lane & 1) * 4] = o;
        int lin = (wave * 4 + i) * 8 + (lane >> 3);
        int t = lin >> 1, bh = lin & 1;
        *(u16x8*)&Bs[nb][(t * 2 + bh) * 64 + (((lane & 7) ^ (t & 7)) << 3)] = bR[i];
      }
    }
    __syncthreads();
  }

  // ---- cross-half reduce + store xp ----
  if (h == 1) {
    #pragma unroll
    for (int nt = 0; nt < 4; ++nt) *(f32x4*)&red[mt][nt][lane][0] = acc[nt];
  }
  __syncthreads();
  if (h == 0) {
    #pragma unroll
    for (int nt = 0; nt < 4; ++nt) {
      f32x4 s2 = acc[nt] + *(const f32x4*)&red[mt][nt][lane][0];
      #pragma unroll
      for (int r = 0; r < 4; ++r)
        xp[(size_t)(r0 + mt * 16 + q * 4 + r) * 64 + nt * 16 + lrow] = f2b(s2[r]);
    }
  }
}

// ---------------- K2: wv = gelu(rownorm(xp@hk^T)) @ hv (fused, sim never in HBM) ----------------
// 512 blocks x 32 rows; wave-private 256-token stripes; chunked wave-private Pl.
__global__ __launch_bounds__(256)
void k2_simwv(const unsigned short* __restrict__ xp, const unsigned short* __restrict__ hkb,
              const unsigned short* __restrict__ hvTb, unsigned short* __restrict__ wvout) {
  __shared__ unsigned short Pl[4][32][152];      // 38 KB wave-private P chunks
  __shared__ float redn[4][2][16];
  __shared__ float redw[4][2][4][64][4];         // 32 KB
  const int tid = threadIdx.x, wave = tid >> 6, lane = tid & 63;
  const int lrow = lane & 15, q = lane >> 4;
  const int r0 = blockIdx.x * 32;
  const int tw = wave * 256;

  bf16x8 xb[2][2];
  #pragma unroll
  for (int mi = 0; mi < 2; ++mi)
    #pragma unroll
    for (int kk = 0; kk < 2; ++kk)
      xb[mi][kk] = *(const bf16x8*)&xp[(size_t)(r0 + mi * 16 + lrow) * 64 + kk * 32 + q * 8];

  // simT: lane holds sim[row=mi*16+lrow][tok = tw + t16*16 + q*4 + r]
  f32x4 acc[16][2] = {};
  #pragma unroll
  for (int t16 = 0; t16 < 16; ++t16)
    #pragma unroll
    for (int kk = 0; kk < 2; ++kk) {
      bf16x8 a = *(const bf16x8*)&hkb[(size_t)(tw + t16 * 16 + lrow) * 64 + kk * 32 + q * 8];
      #pragma unroll
      for (int mi = 0; mi < 2; ++mi)
        acc[t16][mi] = __builtin_amdgcn_mfma_f32_16x16x32_bf16(a, xb[mi][kk], acc[t16][mi], 0, 0, 0);
    }

  // row sumsq -> scale
  float ss[2] = {0.f, 0.f};
  #pragma unroll
  for (int t16 = 0; t16 < 16; ++t16)
    #pragma unroll
    for (int mi = 0; mi < 2; ++mi)
      #pragma unroll
      for (int r = 0; r < 4; ++r)
        ss[mi] += acc[t16][mi][r] * acc[t16][mi][r];
  #pragma unroll
  for (int mi = 0; mi < 2; ++mi) {
    ss[mi] += __shfl_xor(ss[mi], 16, 64);
    ss[mi] += __shfl_xor(ss[mi], 32, 64);
  }
  if (q == 0) { redn[wave][0][lrow] = ss[0]; redn[wave][1][lrow] = ss[1]; }
  __syncthreads();
  float scale[2];
  #pragma unroll
  for (int mi = 0; mi < 2; ++mi) {
    float t = redn[0][mi][lrow] + redn[1][mi][lrow] + redn[2][mi][lrow] + redn[3][mi][lrow];
    scale[mi] = 32.0f * rsqrtf(fmaxf(t, 1e-20f));
  }

  // P chunks + wv partial (Pl wave-private: no barrier; same-wave DS in-order)
  f32x4 wva[2][4] = {};
  #pragma unroll
  for (int c = 0; c < 2; ++c) {
    #pragma unroll
    for (int t8 = 0; t8 < 8; ++t8) {
      const int t16 = c * 8 + t8;
      #pragma unroll
      for (int mi = 0; mi < 2; ++mi) {
        float g0 = gelu_exact(acc[t16][mi][0] * scale[mi]);
        float g1 = gelu_exact(acc[t16][mi][1] * scale[mi]);
        float g2 = gelu_exact(acc[t16][mi][2] * scale[mi]);
        float g3 = gelu_exact(acc[t16][mi][3] * scale[mi]);
        u32x2 pw;
        pw[0] = (unsigned)f2b(g0) | ((unsigned)f2b(g1) << 16);
        pw[1] = (unsigned)f2b(g2) | ((unsigned)f2b(g3) << 16);
        *(u32x2*)&Pl[wave][mi * 16 + lrow][t8 * 16 + q * 4] = pw;
      }
    }
    #pragma unroll
    for (int kc = 0; kc < 4; ++kc) {
      bf16x8 pa0 = *(const bf16x8*)&Pl[wave][lrow][kc * 32 + q * 8];
      bf16x8 pa1 = *(const bf16x8*)&Pl[wave][16 + lrow][kc * 32 + q * 8];
      #pragma unroll
      for (int nt = 0; nt < 4; ++nt) {
        bf16x8 b = *(const bf16x8*)&hvTb[(size_t)(nt * 16 + lrow) * 1024 +
                                         tw + c * 128 + kc * 32 + q * 8];
        wva[0][nt] = __builtin_amdgcn_mfma_f32_16x16x32_bf16(pa0, b, wva[0][nt], 0, 0, 0);
        wva[1][nt] = __builtin_amdgcn_mfma_f32_16x16x32_bf16(pa1, b, wva[1][nt], 0, 0, 0);
      }
    }
  }

  // cross-wave K-reduce; wave w owns j-tile nt=w
  #pragma unroll
  for (int mi = 0; mi < 2; ++mi)
    #pragma unroll
    for (int nt = 0; nt < 4; ++nt)
      *(f32x4*)&redw[wave][mi][nt][lane][0] = wva[mi][nt];
  __syncthreads();
  #pragma unroll
  for (int mi = 0; mi < 2; ++mi) {
    f32x4 s = *(const f32x4*)&redw[0][mi][wave][lane][0];
    s += *(const f32x4*)&redw[1][mi][wave][lane][0];
    s += *(const f32x4*)&redw[2][mi][wave][lane][0];
    s += *(const f32x4*)&redw[3][mi][wave][lane][0];
    #pragma unroll
    for (int r = 0; r < 4; ++r)
      wvout[(size_t)(r0 + mi * 16 + q * 4 + r) * 64 + wave * 16 + lrow] = f2b(s[r]);
  }
}

// ---------------- K3: out[16384,2048] f32 = wv @ Wv2T^T (LDS-staged, coalesced stores) ----
// 512 blocks x 32 rows; 16 f-chunks of 128; slab loads 1KB-contiguous; stores 2x512B runs.
__global__ __launch_bounds__(256)
void k3_out(const unsigned short* __restrict__ wv, const unsigned short* __restrict__ Wv2Tb,
            float* __restrict__ out) {
  __shared__ unsigned short Ws[2][8192];   // slab dbuf [128 f][64 j] swizzled
  __shared__ unsigned short wvs[2048];     // [32 m][64 j] swizzled
  __shared__ float oS[32][136];            // 17.4 KB out staging
  const int tid = threadIdx.x, wave = tid >> 6, lane = tid & 63;
  const int lrow = lane & 15, q = lane >> 4;
  const int r0 = blockIdx.x * 32;

  // stage wv tile (contiguous 128B runs)
  {
    int lin = wave * 64 + lane;            // 0..255
    int row = lin >> 3, u = lin & 7;
    u16x8 v = *(const u16x8*)&wv[(size_t)(r0 + row) * 64 + u * 8];
    *(u16x8*)&wvs[row * 64 + ((u ^ (row & 7)) << 3)] = v;
  }
  u16x8 wR[4];
  // prologue: slab 0 loads
  #pragma unroll
  for (int i = 0; i < 4; ++i) {
    int lin = (wave * 4 + i) * 64 + lane;  // 0..1023
    int frow = lin >> 3, u = lin & 7;
    wR[i] = *(const u16x8*)&Wv2Tb[(size_t)frow * 64 + u * 8];
  }
  #pragma unroll
  for (int i = 0; i < 4; ++i) {
    int lin = (wave * 4 + i) * 64 + lane;
    int frow = lin >> 3, u = lin & 7;
    *(u16x8*)&Ws[0][frow * 64 + ((u ^ (frow & 7)) << 3)] = wR[i];
  }
  __syncthreads();

  // wv B-frags held for whole kernel
  bf16x8 bw[2][2];
  #pragma unroll
  for (int mt = 0; mt < 2; ++mt)
    #pragma unroll
    for (int kk = 0; kk < 2; ++kk) {
      int row = mt * 16 + lrow;
      bw[mt][kk] = *(const bf16x8*)&wvs[row * 64 + (((kk * 4 + q) ^ (row & 7)) << 3)];
    }

  #pragma unroll 1
  for (int fc = 0; fc < 16; ++fc) {
    const int cb = fc & 1, nb = cb ^ 1;
    const bool pf = (fc + 1) < 16;
    if (pf) {
      #pragma unroll
      for (int i = 0; i < 4; ++i) {
        int lin = (wave * 4 + i) * 64 + lane;
        int frow = lin >> 3, u = lin & 7;
        wR[i] = *(const u16x8*)&Wv2Tb[(size_t)((fc + 1) * 128 + frow) * 64 + u * 8];
      }
    }
    // compute 2 f-tiles per wave; D: lane holds out[m=mt*16+lrow][f=ft*16+q*4+r]
    #pragma unroll
    for (int ftl = 0; ftl < 2; ++ftl) {
      const int ft = wave * 2 + ftl;
      f32x4 a2[2] = {};
      #pragma unroll
      for (int kk = 0; kk < 2; ++kk) {
        const int frow = ft * 16 + lrow;
        bf16x8 af = *(const bf16x8*)&Ws[cb][frow * 64 + (((kk * 4 + q) ^ (frow & 7)) << 3)];
        #pragma unroll
        for (int mt = 0; mt < 2; ++mt)
          a2[mt] = __builtin_amdgcn_mfma_f32_16x16x32_bf16(af, bw[mt][kk], a2[mt], 0, 0, 0);
      }
      #pragma unroll
      for (int mt = 0; mt < 2; ++mt)
        *(f32x4*)&oS[mt * 16 + lrow][ft * 16 + q * 4] = a2[mt];
    }
    if (pf) {
      #pragma unroll
      for (int i = 0; i < 4; ++i) {
        int lin = (wave * 4 + i) * 64 + lane;
        int frow = lin >> 3, u = lin & 7;
        *(u16x8*)&Ws[nb][frow * 64 + ((u ^ (frow & 7)) << 3)] = wR[i];
      }
    }
    __syncthreads();
    // coalesced stores: 2 rows x 512B per instr
    #pragma unroll
    for (int i = 0; i < 4; ++i) {
      int row = (wave * 4 + i) * 2 + (lane >> 5);
      int c = (lane & 31) * 4;
      f32x4 v = *(const f32x4*)&oS[row][c];
      *(f32x4*)&out[(size_t)(r0 + row) * 2048 + fc * 128 + c] = v;
    }
    __syncthreads();
  }
}

extern "C" void kernel_launch(void* const* d_in, const int* in_sizes, int n_in,
                              void* d_out, int out_size, void* d_ws, size_t ws_size,
                              hipStream_t stream) {
  (void)in_sizes; (void)n_in; (void)out_size; (void)ws_size;
  const float* x      = (const float*)d_in[0];
  const float* tokens = (const float*)d_in[1];
  const float* Wk1    = (const float*)d_in[2];
  const float* Wk2    = (const float*)d_in[3];
  const float* Wv1    = (const float*)d_in[4];
  const float* Wv2    = (const float*)d_in[5];

  char* ws = (char*)d_ws;
  unsigned short* hkb   = (unsigned short*)(ws);                    // 128 KB
  unsigned short* hvTb  = (unsigned short*)(ws + 131072);           // 128 KB
  unsigned short* Wk2b  = (unsigned short*)(ws + 262144);           // 256 KB
  unsigned short* Wv2Tb = (unsigned short*)(ws + 524288);           // 256 KB
  unsigned short* xp    = (unsigned short*)(ws + (size_t)1 * 1024 * 1024);  // 2 MB
  unsigned short* wvb   = (unsigned short*)(ws + (size_t)3 * 1024 * 1024);  // 2 MB

  hipLaunchKernelGGL(prep, dim3(304), dim3(256), 0, stream,
                     tokens, Wk1, Wv1, Wk2, Wv2, hkb, hvTb, Wk2b, Wv2Tb);
  hipLaunchKernelGGL(k1_xp, dim3(512), dim3(256), 0, stream, x, Wk2b, xp);
  hipLaunchKernelGGL(k2_simwv, dim3(512), dim3(256), 0, stream, xp, hkb, hvTb, wvb);
  hipLaunchKernelGGL(k3_out, dim3(512), dim3(256), 0, stream, wvb, Wv2Tb, (float*)d_out);
}

// Round 11
// 75.963 us; speedup vs baseline: 1.6749x; 1.4473x over previous
//
#include <hip/hip_runtime.h>
#include <hip/hip_bf16.h>
#include <math.h>

typedef __attribute__((ext_vector_type(4))) float f32x4;
typedef __attribute__((ext_vector_type(8))) short bf16x8;     // 8 bf16 in 4 VGPRs
typedef __attribute__((ext_vector_type(4))) unsigned short u16x4;
typedef __attribute__((ext_vector_type(8))) unsigned short u16x8;
typedef __attribute__((ext_vector_type(2))) unsigned int u32x2;

__device__ __forceinline__ unsigned short f2b(float f) {
  unsigned int u = __builtin_bit_cast(unsigned int, f);
  u += 0x7fffu + ((u >> 16) & 1u);          // RNE
  return (unsigned short)(u >> 16);
}
__device__ __forceinline__ float gelu_exact(float x) {
  return 0.5f * x * (1.0f + erff(x * 0.70710678118654752440f));
}

// ---------------- prep: token MLP hiddens + weight conversions ----------------
__global__ void prep(const float* __restrict__ tokens,
                     const float* __restrict__ Wk1, const float* __restrict__ Wv1,
                     const float* __restrict__ Wk2, const float* __restrict__ Wv2,
                     unsigned short* __restrict__ hkb, unsigned short* __restrict__ hvTb,
                     unsigned short* __restrict__ Wk2b, unsigned short* __restrict__ Wv2Tb) {
  const int tid = threadIdx.x;
  const int bx = blockIdx.x;
  if (bx < 256) {
    __shared__ float tok[4][64];
    const int tl = tid >> 6, j = tid & 63;
    const int t0 = bx * 4;
    tok[tl][j] = tokens[(size_t)(t0 + tl) * 64 + j];
    __syncthreads();
    float sk = 0.f, sv = 0.f;
    #pragma unroll 16
    for (int i = 0; i < 64; ++i) {
      float tv = tok[tl][i];
      sk += tv * Wk1[i * 64 + j];
      sv += tv * Wv1[i * 64 + j];
    }
    hkb[(size_t)(t0 + tl) * 64 + j]  = f2b(gelu_exact(sk));
    hvTb[(size_t)j * 1024 + t0 + tl] = f2b(gelu_exact(sv));
  } else if (bx < 272) {
    const int b = bx - 256;
    for (int i = 0; i < 8; ++i) {
      int idx = b * 2048 + i * 256 + tid;
      f32x4 v = ((const f32x4*)Wk2)[idx];
      u16x4 o; o[0] = f2b(v[0]); o[1] = f2b(v[1]); o[2] = f2b(v[2]); o[3] = f2b(v[3]);
      ((u16x4*)Wk2b)[idx] = o;
    }
  } else {
    __shared__ float t[64][65];
    const int f0 = (bx - 272) * 64;
    for (int i = 0; i < 16; ++i) {
      int idx = i * 256 + tid; int r = idx >> 6, c = idx & 63;   // r=j, c=f
      t[r][c] = Wv2[(size_t)r * 2048 + f0 + c];
    }
    __syncthreads();
    for (int i = 0; i < 16; ++i) {
      int idx = i * 256 + tid; int r = idx >> 6, c = idx & 63;   // r=f, c=j
      Wv2Tb[(size_t)(f0 + r) * 64 + c] = f2b(t[c][r]);
    }
  }
}

// ---------------- fused main: x[32 rows] -> xp -> sim -> norm/gelu -> wv -> out ----------------
// 512 blocks x 256 thr. One pass over x; xp/wv live only in LDS. LDS arena (75 KB, 2 blk/CU):
//   P1: As@0 (16K) Bs@16K (32K) red@48K (8K) | xw16@56K (4.5K, written after P1 barrier)
//   P2: Pl@0 (38K) redn@38K (.5K) redw@38.5K (32K)   [xw16 read before redw written]
//   P3: Ws@0 (32K) wvs@32K (4K) oS@36K (17K)          [each reuse barrier-separated]
__global__ __launch_bounds__(256, 2)
void mainK(const float* __restrict__ x,
           const unsigned short* __restrict__ Wk2b,
           const unsigned short* __restrict__ hkb,
           const unsigned short* __restrict__ hvTb,
           const unsigned short* __restrict__ Wv2Tb,
           float* __restrict__ out) {
  __shared__ __align__(16) char smraw[76800];
  // phase-1 views
  unsigned short* As = (unsigned short*)smraw;                                  // [2][4096]
  unsigned short* Bs = (unsigned short*)(smraw + 16384);                        // [2][8192]
  float (*red)[4][64][4] = (float(*)[4][64][4])(smraw + 49152);                 // [2][4][64][4]
  unsigned short (*xw16)[72] = (unsigned short(*)[72])(smraw + 57344);          // [32][72]
  // phase-2 views
  unsigned short (*Pl)[32][152] = (unsigned short(*)[32][152])smraw;            // [4][32][152]
  float (*redn)[2][16] = (float(*)[2][16])(smraw + 38912);                      // [4][2][16]
  float (*redw)[2][4][64][4] = (float(*)[2][4][64][4])(smraw + 39424);          // [4][2][4][64][4]
  // phase-3 views
  unsigned short* Ws = (unsigned short*)smraw;                                  // [2][8192]
  unsigned short* wvs = (unsigned short*)(smraw + 32768);                       // [2048]
  float (*oS)[136] = (float(*)[136])(smraw + 36864);                            // [32][136]

  const int tid = threadIdx.x, wave = tid >> 6, lane = tid & 63;
  const int lrow = lane & 15, q = lane >> 4;
  const int r0 = blockIdx.x * 32;
  const int tw = wave * 256;

  // ================= phase 1: xp32 = x32 @ Wk2b^T =================
  {
    const int mt = wave & 1, h = wave >> 1;
    f32x4 aR[4]; u16x8 bR[4];
    f32x4 acc[4] = {};

    #pragma unroll
    for (int i = 0; i < 4; ++i) {
      int u4 = (wave * 4 + i) * 4 + (lane >> 4);
      int r = u4 >> 1, ah = u4 & 1;
      aR[i] = *(const f32x4*)&x[(size_t)(r0 + r) * 2048 + ah * 1024 + (lane & 15) * 4];
      int lin = (wave * 4 + i) * 8 + (lane >> 3);
      int t = lin >> 1, bh = lin & 1;
      bR[i] = *(const u16x8*)&Wk2b[(size_t)t * 2048 + bh * 1024 + (lane & 7) * 8];
    }
    #pragma unroll
    for (int i = 0; i < 4; ++i) {
      int u4 = (wave * 4 + i) * 4 + (lane >> 4);
      int r = u4 >> 1, ah = u4 & 1;
      int uu = ((lane & 15) >> 1) ^ (r & 7);
      u16x4 o;
      o[0] = f2b(aR[i][0]); o[1] = f2b(aR[i][1]); o[2] = f2b(aR[i][2]); o[3] = f2b(aR[i][3]);
      *(u16x4*)&As[(r * 2 + ah) * 64 + (uu << 3) + (lane & 1) * 4] = o;
      int lin = (wave * 4 + i) * 8 + (lane >> 3);
      int t = lin >> 1, bh = lin & 1;
      *(u16x8*)&Bs[(t * 2 + bh) * 64 + (((lane & 7) ^ (t & 7)) << 3)] = bR[i];
    }
    __syncthreads();

    #pragma unroll 1
    for (int s = 0; s < 16; ++s) {
      const int cb = s & 1, nb = cb ^ 1;
      const bool pf = (s + 1) < 16;
      if (pf) {
        #pragma unroll
        for (int i = 0; i < 4; ++i) {
          int u4 = (wave * 4 + i) * 4 + (lane >> 4);
          int r = u4 >> 1, ah = u4 & 1;
          aR[i] = *(const f32x4*)&x[(size_t)(r0 + r) * 2048 + ah * 1024 + (s + 1) * 64 + (lane & 15) * 4];
          int lin = (wave * 4 + i) * 8 + (lane >> 3);
          int t = lin >> 1, bh = lin & 1;
          bR[i] = *(const u16x8*)&Wk2b[(size_t)t * 2048 + bh * 1024 + (s + 1) * 64 + (lane & 7) * 8];
        }
      }
      #pragma unroll
      for (int kk = 0; kk < 2; ++kk) {
        const int ar = mt * 16 + lrow;
        bf16x8 af = *(const bf16x8*)&As[cb * 4096 + (ar * 2 + h) * 64 + (((kk * 4 + q) ^ (ar & 7)) << 3)];
        #pragma unroll
        for (int nt = 0; nt < 4; ++nt) {
          const int br = nt * 16 + lrow;
          bf16x8 bf = *(const bf16x8*)&Bs[cb * 8192 + (br * 2 + h) * 64 + (((kk * 4 + q) ^ (br & 7)) << 3)];
          acc[nt] = __builtin_amdgcn_mfma_f32_16x16x32_bf16(af, bf, acc[nt], 0, 0, 0);
        }
      }
      if (pf) {
        #pragma unroll
        for (int i = 0; i < 4; ++i) {
          int u4 = (wave * 4 + i) * 4 + (lane >> 4);
          int r = u4 >> 1, ah = u4 & 1;
          int uu = ((lane & 15) >> 1) ^ (r & 7);
          u16x4 o;
          o[0] = f2b(aR[i][0]); o[1] = f2b(aR[i][1]); o[2] = f2b(aR[i][2]); o[3] = f2b(aR[i][3]);
          *(u16x4*)&As[nb * 4096 + (r * 2 + ah) * 64 + (uu << 3) + (lane & 1) * 4] = o;
          int lin = (wave * 4 + i) * 8 + (lane >> 3);
          int t = lin >> 1, bh = lin & 1;
          *(u16x8*)&Bs[nb * 8192 + (t * 2 + bh) * 64 + (((lane & 7) ^ (t & 7)) << 3)] = bR[i];
        }
      }
      __syncthreads();
    }

    // cross-half reduce -> xw16 (LDS), no HBM
    if (h == 1) {
      #pragma unroll
      for (int nt = 0; nt < 4; ++nt) *(f32x4*)&red[mt][nt][lane][0] = acc[nt];
    }
    __syncthreads();
    if (h == 0) {
      #pragma unroll
      for (int nt = 0; nt < 4; ++nt) {
        f32x4 s2 = acc[nt] + *(const f32x4*)&red[mt][nt][lane][0];
        #pragma unroll
        for (int r = 0; r < 4; ++r)
          xw16[mt * 16 + q * 4 + r][nt * 16 + lrow] = f2b(s2[r]);
      }
    }
    __syncthreads();
  }

  // ================= phase 2: sim -> norm -> gelu -> wv (all on-chip) =================
  {
    bf16x8 xb[2][2];
    #pragma unroll
    for (int mi = 0; mi < 2; ++mi)
      #pragma unroll
      for (int kk = 0; kk < 2; ++kk)
        xb[mi][kk] = *(const bf16x8*)&xw16[mi * 16 + lrow][kk * 32 + q * 8];

    // simT: lane holds sim[row=mi*16+lrow][tok = tw + t16*16 + q*4 + r]
    f32x4 acc[16][2] = {};
    #pragma unroll
    for (int t16 = 0; t16 < 16; ++t16)
      #pragma unroll
      for (int kk = 0; kk < 2; ++kk) {
        bf16x8 a = *(const bf16x8*)&hkb[(size_t)(tw + t16 * 16 + lrow) * 64 + kk * 32 + q * 8];
        #pragma unroll
        for (int mi = 0; mi < 2; ++mi)
          acc[t16][mi] = __builtin_amdgcn_mfma_f32_16x16x32_bf16(a, xb[mi][kk], acc[t16][mi], 0, 0, 0);
      }

    float ss[2] = {0.f, 0.f};
    #pragma unroll
    for (int t16 = 0; t16 < 16; ++t16)
      #pragma unroll
      for (int mi = 0; mi < 2; ++mi)
        #pragma unroll
        for (int r = 0; r < 4; ++r)
          ss[mi] += acc[t16][mi][r] * acc[t16][mi][r];
    #pragma unroll
    for (int mi = 0; mi < 2; ++mi) {
      ss[mi] += __shfl_xor(ss[mi], 16, 64);
      ss[mi] += __shfl_xor(ss[mi], 32, 64);
    }
    if (q == 0) { redn[wave][0][lrow] = ss[0]; redn[wave][1][lrow] = ss[1]; }
    __syncthreads();
    float scale[2];
    #pragma unroll
    for (int mi = 0; mi < 2; ++mi) {
      float t = redn[0][mi][lrow] + redn[1][mi][lrow] + redn[2][mi][lrow] + redn[3][mi][lrow];
      scale[mi] = 32.0f * rsqrtf(fmaxf(t, 1e-20f));
    }

    // P chunks + wv partial (Pl wave-private; same-wave DS ops are in-order)
    f32x4 wva[2][4] = {};
    #pragma unroll
    for (int c = 0; c < 2; ++c) {
      #pragma unroll
      for (int t8 = 0; t8 < 8; ++t8) {
        const int t16 = c * 8 + t8;
        #pragma unroll
        for (int mi = 0; mi < 2; ++mi) {
          float g0 = gelu_exact(acc[t16][mi][0] * scale[mi]);
          float g1 = gelu_exact(acc[t16][mi][1] * scale[mi]);
          float g2 = gelu_exact(acc[t16][mi][2] * scale[mi]);
          float g3 = gelu_exact(acc[t16][mi][3] * scale[mi]);
          u32x2 pw;
          pw[0] = (unsigned)f2b(g0) | ((unsigned)f2b(g1) << 16);
          pw[1] = (unsigned)f2b(g2) | ((unsigned)f2b(g3) << 16);
          *(u32x2*)&Pl[wave][mi * 16 + lrow][t8 * 16 + q * 4] = pw;
        }
      }
      #pragma unroll
      for (int kc = 0; kc < 4; ++kc) {
        bf16x8 pa0 = *(const bf16x8*)&Pl[wave][lrow][kc * 32 + q * 8];
        bf16x8 pa1 = *(const bf16x8*)&Pl[wave][16 + lrow][kc * 32 + q * 8];
        #pragma unroll
        for (int nt = 0; nt < 4; ++nt) {
          bf16x8 b = *(const bf16x8*)&hvTb[(size_t)(nt * 16 + lrow) * 1024 +
                                           tw + c * 128 + kc * 32 + q * 8];
          wva[0][nt] = __builtin_amdgcn_mfma_f32_16x16x32_bf16(pa0, b, wva[0][nt], 0, 0, 0);
          wva[1][nt] = __builtin_amdgcn_mfma_f32_16x16x32_bf16(pa1, b, wva[1][nt], 0, 0, 0);
        }
      }
    }

    // cross-wave K-reduce -> wvs (swizzled LDS), no HBM
    #pragma unroll
    for (int mi = 0; mi < 2; ++mi)
      #pragma unroll
      for (int nt = 0; nt < 4; ++nt)
        *(f32x4*)&redw[wave][mi][nt][lane][0] = wva[mi][nt];
    __syncthreads();
    #pragma unroll
    for (int mi = 0; mi < 2; ++mi) {
      f32x4 s = *(const f32x4*)&redw[0][mi][wave][lane][0];
      s += *(const f32x4*)&redw[1][mi][wave][lane][0];
      s += *(const f32x4*)&redw[2][mi][wave][lane][0];
      s += *(const f32x4*)&redw[3][mi][wave][lane][0];
      #pragma unroll
      for (int r = 0; r < 4; ++r) {
        int m = mi * 16 + q * 4 + r, j = wave * 16 + lrow;
        wvs[m * 64 + (((j >> 3) ^ (m & 7)) << 3) + (j & 7)] = f2b(s[r]);
      }
    }
    __syncthreads();
  }

  // ================= phase 3: out32x2048 = wv32 @ Wv2T^T =================
  {
    u16x8 wR[4];
    #pragma unroll
    for (int i = 0; i < 4; ++i) {
      int lin = (wave * 4 + i) * 64 + lane;
      int frow = lin >> 3, u = lin & 7;
      wR[i] = *(const u16x8*)&Wv2Tb[(size_t)frow * 64 + u * 8];
    }
    #pragma unroll
    for (int i = 0; i < 4; ++i) {
      int lin = (wave * 4 + i) * 64 + lane;
      int frow = lin >> 3, u = lin & 7;
      *(u16x8*)&Ws[frow * 64 + ((u ^ (frow & 7)) << 3)] = wR[i];
    }
    __syncthreads();

    bf16x8 bw[2][2];
    #pragma unroll
    for (int mt = 0; mt < 2; ++mt)
      #pragma unroll
      for (int kk = 0; kk < 2; ++kk) {
        int row = mt * 16 + lrow;
        bw[mt][kk] = *(const bf16x8*)&wvs[row * 64 + (((kk * 4 + q) ^ (row & 7)) << 3)];
      }

    #pragma unroll 1
    for (int fc = 0; fc < 16; ++fc) {
      const int cb = fc & 1, nb = cb ^ 1;
      const bool pf = (fc + 1) < 16;
      if (pf) {
        #pragma unroll
        for (int i = 0; i < 4; ++i) {
          int lin = (wave * 4 + i) * 64 + lane;
          int frow = lin >> 3, u = lin & 7;
          wR[i] = *(const u16x8*)&Wv2Tb[(size_t)((fc + 1) * 128 + frow) * 64 + u * 8];
        }
      }
      #pragma unroll
      for (int ftl = 0; ftl < 2; ++ftl) {
        const int ft = wave * 2 + ftl;
        f32x4 a2[2] = {};
        #pragma unroll
        for (int kk = 0; kk < 2; ++kk) {
          const int frow = ft * 16 + lrow;
          bf16x8 af = *(const bf16x8*)&Ws[cb * 8192 + frow * 64 + (((kk * 4 + q) ^ (frow & 7)) << 3)];
          #pragma unroll
          for (int mt = 0; mt < 2; ++mt)
            a2[mt] = __builtin_amdgcn_mfma_f32_16x16x32_bf16(af, bw[mt][kk], a2[mt], 0, 0, 0);
        }
        #pragma unroll
        for (int mt = 0; mt < 2; ++mt)
          *(f32x4*)&oS[mt * 16 + lrow][ft * 16 + q * 4] = a2[mt];
      }
      if (pf) {
        #pragma unroll
        for (int i = 0; i < 4; ++i) {
          int lin = (wave * 4 + i) * 64 + lane;
          int frow = lin >> 3, u = lin & 7;
          *(u16x8*)&Ws[nb * 8192 + frow * 64 + ((u ^ (frow & 7)) << 3)] = wR[i];
        }
      }
      __syncthreads();
      #pragma unroll
      for (int i = 0; i < 4; ++i) {
        int row = (wave * 4 + i) * 2 + (lane >> 5);
        int c = (lane & 31) * 4;
        f32x4 v = *(const f32x4*)&oS[row][c];
        *(f32x4*)&out[(size_t)(r0 + row) * 2048 + fc * 128 + c] = v;
      }
      __syncthreads();
    }
  }
}

extern "C" void kernel_launch(void* const* d_in, const int* in_sizes, int n_in,
                              void* d_out, int out_size, void* d_ws, size_t ws_size,
                              hipStream_t stream) {
  (void)in_sizes; (void)n_in; (void)out_size; (void)ws_size;
  const float* x      = (const float*)d_in[0];
  const float* tokens = (const float*)d_in[1];
  const float* Wk1    = (const float*)d_in[2];
  const float* Wk2    = (const float*)d_in[3];
  const float* Wv1    = (const float*)d_in[4];
  const float* Wv2    = (const float*)d_in[5];

  char* ws = (char*)d_ws;
  unsigned short* hkb   = (unsigned short*)(ws);                    // 128 KB
  unsigned short* hvTb  = (unsigned short*)(ws + 131072);           // 128 KB
  unsigned short* Wk2b  = (unsigned short*)(ws + 262144);           // 256 KB
  unsigned short* Wv2Tb = (unsigned short*)(ws + 524288);           // 256 KB

  hipLaunchKernelGGL(prep, dim3(304), dim3(256), 0, stream,
                     tokens, Wk1, Wv1, Wk2, Wv2, hkb, hvTb, Wk2b, Wv2Tb);
  hipLaunchKernelGGL(mainK, dim3(512), dim3(256), 0, stream,
                     x, Wk2b, hkb, hvTb, Wv2Tb, (float*)d_out);
}